// Round 4
// baseline (487.675 us; speedup 1.0000x reference)
//
#include <hip/hip_runtime.h>

// GIN (2x GINE conv): direct global-atomic CSR build + scalarized CSR gather
// + bf16 MFMA GEMMs (middle two fused through LDS).
// Pipeline:  K1 wprep  (weights->bf16^T, cnt zero, ptr[N]=E)
//            K2 hist   (atomicAdd cnt[dst])
//            K3 scanA  (per-1024-block exclusive scan of cnt, block sums)
//            K4 scanC  (add scanned block bases -> ptr, ptrw copy)
//            K5 scatter || gemm1  (csr[atomicAdd(ptrw[dst])] = {src, ea}  grid-
//                                  fused with layer-1 GEMM; independent work)
//            K6 gather(A)  -> B   (standalone: 1 node/wave, nt store; proven 59us)
//            K7 fused_mid: relu(B@W12+cnt*b12)@W21+b21 -> A2
//            K8 gather(A2) -> B2
//            K9 B2 @ W22 + cnt*b22 -> out (f32)
// Rounds 2-3 showed gather+GEMM fusion runs the gather at ~2x the standalone
// time regardless of tile size/occupancy -> keep gathers standalone.
// Rounds 0-3 never surfaced bin/bucket_csr in top-5; this round replaces the
// LDS-sort build (~64MB staging + 3.2M LDS atomics) with global-atomic build.

typedef unsigned int uint;
typedef __attribute__((ext_vector_type(8))) short bf16x8;
typedef __attribute__((ext_vector_type(4))) float f32x4;

static __device__ __forceinline__ unsigned short f2bf(float f) {
    uint u = __float_as_uint(f);
    uint r = (u + 0x7fffu + ((u >> 16) & 1u)) >> 16;
    return (unsigned short)r;
}

// ---------------- K1: weight prep + cnt zero + ptr[N]=E ----------------

__global__ void wprep_all(const float* __restrict__ W11, const float* __restrict__ W12,
                          const float* __restrict__ W21, const float* __restrict__ W22,
                          unsigned short* Wt11, unsigned short* Wt12,
                          unsigned short* Wt21, unsigned short* Wt22,
                          int* cnt, int* ptr, int N, int E) {
    int idx = blockIdx.x * 256 + threadIdx.x;
    if (idx < N) cnt[idx] = 0;
    if (idx == 0) ptr[N] = E;
    const float* W; unsigned short* Wt; int K; int off;
    if (idx < 64 * 128)        { W = W11; Wt = Wt11; K = 64;  off = idx; }
    else if (idx < 192 * 128)  { W = W12; Wt = Wt12; K = 128; off = idx - 64 * 128; }
    else if (idx < 320 * 128)  { W = W21; Wt = Wt21; K = 128; off = idx - 192 * 128; }
    else if (idx < 448 * 128)  { W = W22; Wt = Wt22; K = 128; off = idx - 320 * 128; }
    else return;
    int k = off >> 7, n = off & 127;
    Wt[n * K + k] = f2bf(W[k * 128 + n]);
}

// ---------------- K2: degree histogram (global atomics, 100K targets) ----------------

__global__ __launch_bounds__(512) void hist_kernel(
    const int* __restrict__ dst, int* __restrict__ cnt, int E) {
    const int base = blockIdx.x * 4096 + threadIdx.x;
#pragma unroll
    for (int k = 0; k < 8; k++) {
        int i = base + k * 512;
        if (i < E) atomicAdd(&cnt[dst[i]], 1);
    }
}

// ---------------- K3: per-block exclusive scan of cnt (in place) + block sums ----------------

__global__ __launch_bounds__(1024) void scanA(
    int* __restrict__ cnt, int* __restrict__ bsum, int N) {
    __shared__ int wt[16];
    const int tid = threadIdx.x;
    const int lane = tid & 63, wid = tid >> 6;
    const int i = blockIdx.x * 1024 + tid;
    int v = (i < N) ? cnt[i] : 0;
    int inc = v;
#pragma unroll
    for (int off = 1; off < 64; off <<= 1) {
        int t = __shfl_up(inc, off, 64);
        if (lane >= off) inc += t;
    }
    if (lane == 63) wt[wid] = inc;
    __syncthreads();
    int add = 0;
#pragma unroll
    for (int j = 0; j < 16; j++) add += (j < wid) ? wt[j] : 0;
    if (i < N) cnt[i] = inc - v + add;     // exclusive within block
    if (tid == 1023) bsum[blockIdx.x] = add + inc;   // block total
}

// ---------------- K4: add scanned block bases -> ptr, and ptrw working copy ----------------

__global__ __launch_bounds__(1024) void scanC(
    const int* __restrict__ cnt, const int* __restrict__ bsum,
    int* __restrict__ ptr, int* __restrict__ ptrw, int N, int NB) {
    __shared__ int sb[128];
    __shared__ int bb;
    const int tid = threadIdx.x;
    if (tid < 128) sb[tid] = (tid < NB) ? bsum[tid] : 0;
    __syncthreads();
    if (tid == 0) {
        int run = 0;
        for (int j = 0; j < (int)blockIdx.x; j++) run += sb[j];
        bb = run;
    }
    __syncthreads();
    const int i = blockIdx.x * 1024 + tid;
    if (i < N) {
        int p = cnt[i] + bb;
        ptr[i] = p;
        ptrw[i] = p;
    }
}

// ---------------- MFMA GEMM body: C[rowBase..+64][128] = A @ W[K][128] + bias ----------------

template <int K, bool IN_F32, bool OUT_BF16, bool USE_CNT, bool RELU>
static __device__ __forceinline__ void gemm_body(
    const void* __restrict__ Ain, const unsigned short* __restrict__ Wt,
    const float* __restrict__ bias, const int* __restrict__ ptr,
    void* __restrict__ Cout, int N, int tid, long rowBase) {
    constexpr int KS = K / 32;
    const int wave = tid >> 6;
    const int lane = tid & 63;
    const int m = lane & 15, quad = lane >> 4;

    bf16x8 bfrag[2][KS];
#pragma unroll
    for (int ct = 0; ct < 2; ct++) {
        int col = (wave * 2 + ct) * 16 + m;
#pragma unroll
        for (int ks = 0; ks < KS; ks++)
            bfrag[ct][ks] = *(const bf16x8*)(Wt + (long)col * K + ks * 32 + quad * 8);
    }

#pragma unroll
    for (int rt = 0; rt < 4; rt++) {
        long row = rowBase + rt * 16 + m;
        long rc = row < N ? row : (long)N - 1;
        bf16x8 afrag[KS];
        if (IN_F32) {
            const float* arow = (const float*)Ain + rc * K;
#pragma unroll
            for (int ks = 0; ks < KS; ks++) {
                float4 lo = *(const float4*)(arow + ks * 32 + quad * 8);
                float4 hi = *(const float4*)(arow + ks * 32 + quad * 8 + 4);
                bf16x8 f;
                f[0] = (short)f2bf(lo.x); f[1] = (short)f2bf(lo.y);
                f[2] = (short)f2bf(lo.z); f[3] = (short)f2bf(lo.w);
                f[4] = (short)f2bf(hi.x); f[5] = (short)f2bf(hi.y);
                f[6] = (short)f2bf(hi.z); f[7] = (short)f2bf(hi.w);
                afrag[ks] = f;
            }
        } else {
            const unsigned short* arow = (const unsigned short*)Ain + rc * K;
#pragma unroll
            for (int ks = 0; ks < KS; ks++)
                afrag[ks] = *(const bf16x8*)(arow + ks * 32 + quad * 8);
        }

#pragma unroll
        for (int ct = 0; ct < 2; ct++) {
            f32x4 acc = {0.f, 0.f, 0.f, 0.f};
#pragma unroll
            for (int ks = 0; ks < KS; ks++)
                acc = __builtin_amdgcn_mfma_f32_16x16x32_bf16(afrag[ks], bfrag[ct][ks], acc, 0, 0, 0);

            int col = (wave * 2 + ct) * 16 + m;
            float b = bias[col];
#pragma unroll
            for (int r = 0; r < 4; r++) {
                long orow = rowBase + rt * 16 + quad * 4 + r;
                if (orow < N) {
                    float v = acc[r];
                    if (USE_CNT) v += b * (float)(ptr[orow + 1] - ptr[orow] + 1);
                    else v += b;
                    if (RELU) v = fmaxf(v, 0.f);
                    if (OUT_BF16) ((unsigned short*)Cout)[orow * 128 + col] = f2bf(v);
                    else ((float*)Cout)[orow * 128 + col] = v;
                }
            }
        }
    }
}

// ---------------- K5: scatter (csr fill via atomic rank) || layer-1 GEMM ----------------

__global__ __launch_bounds__(512) void scatter_gemm1(
    const int* __restrict__ src, const int* __restrict__ dst,
    const float* __restrict__ ea, int* __restrict__ ptrw,
    int2* __restrict__ csr, int SB, int E,
    const float* __restrict__ x, const unsigned short* __restrict__ Wt11,
    const float* __restrict__ b11, unsigned short* __restrict__ A_bf, int N) {
    if ((int)blockIdx.x < SB) {
        const int base = blockIdx.x * 4096 + threadIdx.x;
#pragma unroll
        for (int k = 0; k < 8; k++) {
            int i = base + k * 512;
            if (i < E) {
                int s = src[i], d = dst[i];
                float2 a = reinterpret_cast<const float2*>(ea)[i];
                int pos = atomicAdd(&ptrw[d], 1);
                int2 o;
                o.x = s;
                o.y = (int)((uint)f2bf(a.x) | ((uint)f2bf(a.y) << 16));
                csr[pos] = o;
            }
        }
    } else {
        int bid = blockIdx.x - SB;
        int sub = threadIdx.x >> 8;  // two 64-row tiles per 512-thread block
        gemm_body<64, true, true, false, false>(x, Wt11, b11, nullptr, A_bf, N,
                                                threadIdx.x & 255,
                                                (long)bid * 128 + sub * 64);
    }
}

// ---------------- K6/K8: CSR gather, wave/node, scalarized edge stream (round-1 proven) ----------------

__global__ __launch_bounds__(256) void gather_kernel(
    const uint* __restrict__ Au, const int* __restrict__ ptr,
    const int2* __restrict__ csr, const float* __restrict__ we,
    uint* __restrict__ Bout, int N) {
    int node = blockIdx.x * 4 + (threadIdx.x >> 6);
    if (node >= N) return;
    node = __builtin_amdgcn_readfirstlane(node);
    const int t = threadIdx.x & 63;
    const int c = 2 * t;
    const float w0x = we[c], w0y = we[c + 1];
    const float w1x = we[128 + c], w1y = we[128 + c + 1];

    const char* Ab = (const char*)Au;
    const uint t4 = (uint)t * 4u;
#define LD(sidx) (*(const uint*)(Ab + ((((uint)(sidx)) << 8) + t4)))
#define ACC(rv, ev)                                                      \
    {                                                                    \
        float a0 = __uint_as_float(((uint)(ev)) << 16);                  \
        float a1 = __uint_as_float(((uint)(ev)) & 0xffff0000u);          \
        float vx = __uint_as_float((rv) << 16);                          \
        float vy = __uint_as_float((rv) & 0xffff0000u);                  \
        vx = fmaf(a0, w0x, fmaf(a1, w1x, vx));                           \
        vy = fmaf(a0, w0y, fmaf(a1, w1y, vy));                           \
        ax += fmaxf(vx, 0.f);                                            \
        ay += fmaxf(vy, 0.f);                                            \
    }
#define EDGE(i, off)                                                     \
    int2 c##i = csr[k + (off)];                                          \
    uint s##i = (uint)__builtin_amdgcn_readfirstlane(c##i.x);            \
    uint e##i = (uint)__builtin_amdgcn_readfirstlane(c##i.y);

    uint selfv = LD((uint)node);
    float ax = fmaxf(__uint_as_float(selfv << 16) + w0x + w1x, 0.f);
    float ay = fmaxf(__uint_as_float(selfv & 0xffff0000u) + w0y + w1y, 0.f);

    // wave-uniform edge range -> scalar loop control + scalar csr loads
    int k   = __builtin_amdgcn_readfirstlane(ptr[node]);
    int end = __builtin_amdgcn_readfirstlane(ptr[node + 1]);

    for (; k + 8 <= end; k += 8) {
        EDGE(0, 0) EDGE(1, 1) EDGE(2, 2) EDGE(3, 3)
        EDGE(4, 4) EDGE(5, 5) EDGE(6, 6) EDGE(7, 7)
        uint r0 = LD(s0); uint r1 = LD(s1); uint r2 = LD(s2); uint r3 = LD(s3);
        uint r4 = LD(s4); uint r5 = LD(s5); uint r6 = LD(s6); uint r7 = LD(s7);
        ACC(r0, e0) ACC(r1, e1) ACC(r2, e2) ACC(r3, e3)
        ACC(r4, e4) ACC(r5, e5) ACC(r6, e6) ACC(r7, e7)
    }
    for (; k + 2 <= end; k += 2) {
        EDGE(0, 0) EDGE(1, 1)
        uint r0 = LD(s0); uint r1 = LD(s1);
        ACC(r0, e0) ACC(r1, e1)
    }
    if (k < end) {
        EDGE(0, 0)
        uint r0 = LD(s0);
        ACC(r0, e0)
    }
#undef EDGE
#undef ACC
#undef LD
    uint outv = (uint)f2bf(ax) | ((uint)f2bf(ay) << 16);
    // nt store: B is streamed; don't evict A's L2 lines
    __builtin_nontemporal_store(outv, Bout + (long)node * 64 + t);
}

// ---------------- K7: fused middle GEMMs: A2 = (relu(B@W12 + cnt*b12)) @ W21 + b21 ----------------

__global__ __launch_bounds__(256) void fused_mid_gemm(
    const unsigned short* __restrict__ Bin, const int* __restrict__ ptr,
    const unsigned short* __restrict__ WtA, const float* __restrict__ biasA,
    const unsigned short* __restrict__ WtB, const float* __restrict__ biasB,
    unsigned short* __restrict__ Cout, int N) {
    __shared__ unsigned short ts[64 * 136];
    const int wave = threadIdx.x >> 6;
    const int lane = threadIdx.x & 63;
    const int m = lane & 15, quad = lane >> 4;
    const long rowBase = (long)blockIdx.x * 64;

    bf16x8 bfrag[2][4];
#pragma unroll
    for (int ct = 0; ct < 2; ct++) {
        int col = (wave * 2 + ct) * 16 + m;
#pragma unroll
        for (int ks = 0; ks < 4; ks++)
            bfrag[ct][ks] = *(const bf16x8*)(WtA + (long)col * 128 + ks * 32 + quad * 8);
    }

    f32x4 acc[4][2];
#pragma unroll
    for (int rt = 0; rt < 4; rt++) {
        long row = rowBase + rt * 16 + m;
        long rc = row < N ? row : (long)N - 1;
        const unsigned short* arow = Bin + rc * 128;
        bf16x8 af[4];
#pragma unroll
        for (int ks = 0; ks < 4; ks++)
            af[ks] = *(const bf16x8*)(arow + ks * 32 + quad * 8);
#pragma unroll
        for (int ct = 0; ct < 2; ct++) {
            f32x4 a = {0.f, 0.f, 0.f, 0.f};
#pragma unroll
            for (int ks = 0; ks < 4; ks++)
                a = __builtin_amdgcn_mfma_f32_16x16x32_bf16(af[ks], bfrag[ct][ks], a, 0, 0, 0);
            acc[rt][ct] = a;
        }
    }

#pragma unroll
    for (int rt = 0; rt < 4; rt++) {
        float cntf[4];
#pragma unroll
        for (int r = 0; r < 4; r++) {
            long grow = rowBase + rt * 16 + quad * 4 + r;
            cntf[r] = (grow < N) ? (float)(ptr[grow + 1] - ptr[grow] + 1) : 1.f;
        }
#pragma unroll
        for (int ct = 0; ct < 2; ct++) {
            int col = (wave * 2 + ct) * 16 + m;
            float b = biasA[col];
#pragma unroll
            for (int r = 0; r < 4; r++) {
                int row = rt * 16 + quad * 4 + r;
                ts[row * 136 + col] = f2bf(fmaxf(acc[rt][ct][r] + b * cntf[r], 0.f));
            }
        }
    }
    __syncthreads();

#pragma unroll
    for (int ct = 0; ct < 2; ct++) {
        int col = (wave * 2 + ct) * 16 + m;
#pragma unroll
        for (int ks = 0; ks < 4; ks++)
            bfrag[ct][ks] = *(const bf16x8*)(WtB + (long)col * 128 + ks * 32 + quad * 8);
    }
#pragma unroll
    for (int rt = 0; rt < 4; rt++) {
        const unsigned short* lr = ts + (rt * 16 + m) * 136;
        bf16x8 af[4];
#pragma unroll
        for (int ks = 0; ks < 4; ks++)
            af[ks] = *(const bf16x8*)(lr + ks * 32 + quad * 8);
#pragma unroll
        for (int ct = 0; ct < 2; ct++) {
            f32x4 a = {0.f, 0.f, 0.f, 0.f};
#pragma unroll
            for (int ks = 0; ks < 4; ks++)
                a = __builtin_amdgcn_mfma_f32_16x16x32_bf16(af[ks], bfrag[ct][ks], a, 0, 0, 0);
            int col = (wave * 2 + ct) * 16 + m;
            float b = biasB[col];
#pragma unroll
            for (int r = 0; r < 4; r++) {
                long grow = rowBase + rt * 16 + quad * 4 + r;
                if (grow < N) Cout[grow * 128 + col] = f2bf(a[r] + b);
            }
        }
    }
}

// ---------------- K9: last GEMM wrapper ----------------

template <int K, bool IN_F32, bool OUT_BF16, bool USE_CNT, bool RELU>
__global__ __launch_bounds__(256) void gemm_mfma(
    const void* __restrict__ Ain, const unsigned short* __restrict__ Wt,
    const float* __restrict__ bias, const int* __restrict__ ptr,
    void* __restrict__ Cout, int N) {
    gemm_body<K, IN_F32, OUT_BF16, USE_CNT, RELU>(Ain, Wt, bias, ptr, Cout, N,
                                                  threadIdx.x, (long)blockIdx.x * 64);
}

// ---------------- launch ----------------

extern "C" void kernel_launch(void* const* d_in, const int* in_sizes, int n_in,
                              void* d_out, int out_size, void* d_ws, size_t ws_size,
                              hipStream_t stream) {
    const float* x   = (const float*)d_in[0];
    const int*   ei  = (const int*)d_in[1];
    const float* ea  = (const float*)d_in[2];
    const float* W11 = (const float*)d_in[3];
    const float* b11 = (const float*)d_in[4];
    const float* W12 = (const float*)d_in[5];
    const float* b12 = (const float*)d_in[6];
    const float* W21 = (const float*)d_in[7];
    const float* b21 = (const float*)d_in[8];
    const float* W22 = (const float*)d_in[9];
    const float* b22 = (const float*)d_in[10];
    float* out = (float*)d_out;

    const int N = in_sizes[0] / 64;
    const int E = in_sizes[1] / 2;
    const int* src = ei;
    const int* dst = ei + E;

    char* p = (char*)d_ws;
    unsigned short* A_bf = (unsigned short*)p;  p += (size_t)N * 128 * 2;  // 25.6 MB
    unsigned short* B_bf = (unsigned short*)p;  p += (size_t)N * 128 * 2;  // 25.6 MB
    int2* csr  = (int2*)p;                      p += (size_t)E * 8;        // 12.8 MB
    int* ptr   = (int*)p;                       p += (size_t)(N + 1) * 4;
    int* ptrw  = (int*)p;                       p += (size_t)N * 4;
    int* cnt   = (int*)p;                       p += (size_t)N * 4;        // also holds local-scan
    int* bsum  = (int*)p;                       p += 128 * 4;
    unsigned short* Wt11 = (unsigned short*)p;  p += (size_t)64 * 128 * 2;
    unsigned short* Wt12 = (unsigned short*)p;  p += (size_t)128 * 128 * 2;
    unsigned short* Wt21 = (unsigned short*)p;  p += (size_t)128 * 128 * 2;
    unsigned short* Wt22 = (unsigned short*)p;

    const int SB = (E + 4095) / 4096;             // 391 scatter/hist blocks
    const int NB = (N + 1023) / 1024;             // 98 scan blocks
    const int wprepBlocks = ((N > 448 * 128 ? N : 448 * 128) + 255) / 256;
    const int gatherBlocks = (N + 3) / 4;         // 25000
    const int tileBlocks = (N + 63) / 64;         // 1563
    const int g1Tiles = (N + 127) / 128;          // 782 (128-row tiles, 512 thr)

    wprep_all<<<wprepBlocks, 256, 0, stream>>>(W11, W12, W21, W22,
                                               Wt11, Wt12, Wt21, Wt22,
                                               cnt, ptr, N, E);
    hist_kernel<<<SB, 512, 0, stream>>>(dst, cnt, E);
    scanA<<<NB, 1024, 0, stream>>>(cnt, bsum, N);
    scanC<<<NB, 1024, 0, stream>>>(cnt, bsum, ptr, ptrw, N, NB);
    // csr scatter || layer-1 gemm (independent work, one grid)
    scatter_gemm1<<<SB + g1Tiles, 512, 0, stream>>>(src, dst, ea, ptrw, csr, SB, E,
                                                    x, Wt11, b11, A_bf, N);
    gather_kernel<<<gatherBlocks, 256, 0, stream>>>((const uint*)A_bf, ptr, csr,
                                                    W11 + 64 * 128, (uint*)B_bf, N);
    fused_mid_gemm<<<tileBlocks, 256, 0, stream>>>(B_bf, ptr, Wt12, b12, Wt21, b21, A_bf, N);
    gather_kernel<<<gatherBlocks, 256, 0, stream>>>((const uint*)A_bf, ptr, csr,
                                                    W21 + 128 * 128, (uint*)B_bf, N);
    gemm_mfma<128, false, false, true, false><<<tileBlocks, 256, 0, stream>>>(
        B_bf, Wt22, b22, ptr, out, N);
}